// Round 8
// baseline (54.706 us; speedup 1.0000x reference)
//
#include <hip/hip_runtime.h>
#include <hip/hip_bf16.h>

#define NTOK 32768
#define NE   1024
#define DD   256
#define BM   32

typedef __attribute__((ext_vector_type(4))) float  f32x4;

// ws layout: embp fp8 pack [256 KB] | en10 [4 KB] | flags [4 KB] | emax2 [4 B]

// ---- prep1: en10[row] = -10*||emb_row||^2 ; emax2 = max ||e||^2 (uint bits) ----
__global__ __launch_bounds__(256) void prep_norm_kernel(
    const float* __restrict__ emb, float* __restrict__ en10,
    unsigned int* __restrict__ emax2_bits)
{
    const int t = threadIdx.x;
    const int row = blockIdx.x * 4 + (t >> 6);   // one wave per row
    const int q = t & 63;
    f32x4 v = *(const f32x4*)(emb + (size_t)row * DD + q * 4);
    float ss = v.x * v.x + v.y * v.y + v.z * v.z + v.w * v.w;
#pragma unroll
    for (int off = 32; off; off >>= 1) ss += __shfl_xor(ss, off, 64);
    if (q == 0) {
        en10[row] = -10.f * ss;
        atomicMax(emax2_bits, __float_as_uint(ss));   // ss >= 0: uint cmp == float cmp
    }
}

// ---- prep2: pack fp8(-1024*emb) in MFMA B-fragment-linear order ----
__global__ __launch_bounds__(512) void prep_pack_kernel(
    const float* __restrict__ emb, unsigned char* __restrict__ embp)
{
    const int j2 = blockIdx.x;        // 0..63
    const int kk = threadIdx.x >> 6;  // 0..7
    const int l  = threadIdx.x & 63;
    const int lr = l & 15, lg = l >> 4;
    const float* src = emb + (size_t)(j2 * 16 + lr) * DD + kk * 32 + lg * 8;
    f32x4 a = *(const f32x4*)src;
    f32x4 b = *(const f32x4*)(src + 4);
    const float s = -1024.0f;
    int lo = 0, hi = 0;
    lo = __builtin_amdgcn_cvt_pk_fp8_f32(s * a.x, s * a.y, lo, false);
    lo = __builtin_amdgcn_cvt_pk_fp8_f32(s * a.z, s * a.w, lo, true);
    hi = __builtin_amdgcn_cvt_pk_fp8_f32(s * b.x, s * b.y, hi, false);
    hi = __builtin_amdgcn_cvt_pk_fp8_f32(s * b.z, s * b.w, hi, true);
    uint2 p; p.x = (unsigned)lo; p.y = (unsigned)hi;
    *(uint2*)(embp + ((size_t)(j2 * 8 + kk) * 64 + l) * 8) = p;
}

// ---- fast path: per-row saturation check + uniform fill ----
// Row n: if ||z_n||^2 >= (3 + max||e||)^2 then d >= 9 for every code,
// u = 10*exp(-10d) < 1e-37 << 2^-53, exp(u) == 1.0 exactly (fp32 & fp64)
// -> softmax row is bit-exactly 1/1024. Else flag the row's 32-row tile.
// 4 waves/block, 1 row/wave, no LDS, no barriers: pure streaming.
__global__ __launch_bounds__(256) void check_fill_kernel(
    const float* __restrict__ z, const unsigned int* __restrict__ emax2_bits,
    float* __restrict__ out, unsigned int* __restrict__ flags)
{
    const int w = threadIdx.x >> 6;   // wave 0..3
    const int l = threadIdx.x & 63;
    const int row = blockIdx.x * 4 + w;

    const float E = sqrtf(__uint_as_float(*emax2_bits));
    const float rhs = (3.0f + E) * (3.0f + E);

    f32x4 v = *(const f32x4*)(z + (size_t)row * DD + l * 4);
    float ss = v.x * v.x + v.y * v.y + v.z * v.z + v.w * v.w;
#pragma unroll
    for (int off = 32; off; off >>= 1) ss += __shfl_xor(ss, off, 64);

    if (ss < rhs) {
        if (l == 0) atomicOr(&flags[row >> 5], 1u);
        return;
    }
    const float c = 0.0009765625f;   // 1/1024
    const f32x4 cv = {c, c, c, c};
    float* ob = out + (size_t)row * NE + l * 4;
#pragma unroll
    for (int i = 0; i < 4; ++i)
        *(f32x4*)(ob + i * 256) = cv;
}

// ---- fallback: full fused dist-GEMM + softmax for flagged tiles only ----
__global__ __launch_bounds__(1024, 8) void sq_gemm_kernel(
    const float* __restrict__ z, const unsigned char* __restrict__ embp,
    const float* __restrict__ en10, const unsigned int* __restrict__ flags,
    float* __restrict__ out)
{
    if (flags[blockIdx.x] == 0) return;   // tile already written uniform

    __shared__ alignas(16) unsigned char af[16][65][8];
    __shared__ float zn10_s[BM];
    __shared__ float red[BM][16];
    __shared__ float rowinv[BM];

    const int t  = threadIdx.x;
    const int n0 = blockIdx.x * BM;
    const int w  = t >> 6;
    const int l  = t & 63;

    // stage z: fp32 load, -10*norm, fp8 fragment-linear to LDS
#pragma unroll
    for (int rg = 0; rg < 2; ++rg) {
        const int r = rg * 16 + w;
        f32x4 v = *(const f32x4*)(z + (size_t)(n0 + r) * DD + l * 4);
        float ss = v.x * v.x + v.y * v.y + v.z * v.z + v.w * v.w;
#pragma unroll
        for (int off = 32; off; off >>= 1) ss += __shfl_xor(ss, off, 64);
        if (l == 0) zn10_s[r] = -10.f * ss;
        int pk = 0;
        pk = __builtin_amdgcn_cvt_pk_fp8_f32(v.x, v.y, pk, false);
        pk = __builtin_amdgcn_cvt_pk_fp8_f32(v.z, v.w, pk, true);
        *(unsigned*)&af[rg * 8 + (l >> 3)][((l >> 1) & 3) * 16 + w][(l & 1) * 4] =
            (unsigned)pk;
    }
    __syncthreads();

    const int lr = l & 15, lg = l >> 4;

    f32x4 acc[2][4];
#pragma unroll
    for (int rg = 0; rg < 2; ++rg)
#pragma unroll
        for (int j = 0; j < 4; ++j) acc[rg][j] = (f32x4){0.f, 0.f, 0.f, 0.f};

    const unsigned char* bbase = embp + ((size_t)(w * 4) * 8 * 64 + l) * 8;
#pragma unroll
    for (int kk = 0; kk < 8; ++kk) {
        long a0 = *(const long*)&af[kk][l][0];
        long a1 = *(const long*)&af[8 + kk][l][0];
#pragma unroll
        for (int j = 0; j < 4; ++j) {
            long b = *(const long*)(bbase + (size_t)(j * 8 + kk) * 512);
            acc[0][j] = __builtin_amdgcn_mfma_f32_16x16x32_fp8_fp8(a0, b, acc[0][j], 0, 0, 0);
            acc[1][j] = __builtin_amdgcn_mfma_f32_16x16x32_fp8_fp8(a1, b, acc[1][j], 0, 0, 0);
        }
    }

    float zr10[2][4];
#pragma unroll
    for (int rg = 0; rg < 2; ++rg)
#pragma unroll
        for (int r = 0; r < 4; ++r) zr10[rg][r] = zn10_s[rg * 16 + lg * 4 + r];

    float sum[2][4] = {{0.f, 0.f, 0.f, 0.f}, {0.f, 0.f, 0.f, 0.f}};
#pragma unroll
    for (int j = 0; j < 4; ++j) {
        const float ec10 = en10[w * 64 + j * 16 + lr];
#pragma unroll
        for (int rg = 0; rg < 2; ++rg)
#pragma unroll
            for (int r = 0; r < 4; ++r) {
                const float tt = fmaf(-0.01953125f, acc[rg][j][r], zr10[rg][r] + ec10);
                const float u  = 10.0f * __expf(tt);
                const float e  = __expf(u);
                acc[rg][j][r] = e;
                sum[rg][r] += e;
            }
    }
#pragma unroll
    for (int off = 1; off < 16; off <<= 1)
#pragma unroll
        for (int rg = 0; rg < 2; ++rg)
#pragma unroll
            for (int r = 0; r < 4; ++r) sum[rg][r] += __shfl_xor(sum[rg][r], off, 64);
    if (lr == 0)
#pragma unroll
        for (int rg = 0; rg < 2; ++rg)
#pragma unroll
            for (int r = 0; r < 4; ++r) red[rg * 16 + lg * 4 + r][w] = sum[rg][r];
    __syncthreads();

    if (t < BM) {
        const float* p = red[t];
        float s = 0.f;
#pragma unroll
        for (int q = 0; q < 16; ++q) s += p[q];
        rowinv[t] = 1.0f / s;
    }
    __syncthreads();

    float inv[2][4];
#pragma unroll
    for (int rg = 0; rg < 2; ++rg)
#pragma unroll
        for (int r = 0; r < 4; ++r) inv[rg][r] = rowinv[rg * 16 + lg * 4 + r];

#pragma unroll
    for (int j = 0; j < 4; ++j) {
        const int col = w * 64 + j * 16 + lr;
#pragma unroll
        for (int rg = 0; rg < 2; ++rg)
#pragma unroll
            for (int r = 0; r < 4; ++r) {
                const int row = rg * 16 + lg * 4 + r;
                out[(size_t)(n0 + row) * NE + col] = acc[rg][j][r] * inv[rg][r];
            }
    }
}

extern "C" void kernel_launch(void* const* d_in, const int* in_sizes, int n_in,
                              void* d_out, int out_size, void* d_ws, size_t ws_size,
                              hipStream_t stream) {
    (void)in_sizes; (void)n_in; (void)out_size; (void)ws_size;
    const float* z   = (const float*)d_in[0];
    const float* emb = (const float*)d_in[1];
    float* out = (float*)d_out;
    unsigned char* embp = (unsigned char*)d_ws;                          // 256 KB
    char* base = (char*)d_ws + (size_t)NE * DD;
    float* en10 = (float*)base;                                          // 4 KB
    unsigned int* flags = (unsigned int*)(base + NE * sizeof(float));    // 4 KB
    unsigned int* emax2 = (unsigned int*)(base + NE * sizeof(float)
                                          + (NTOK / BM) * sizeof(unsigned int));

    // zero flags + emax2 in one async memset (graph-safe)
    hipMemsetAsync(flags, 0, (NTOK / BM) * sizeof(unsigned int) + sizeof(unsigned int),
                   stream);
    hipLaunchKernelGGL(prep_norm_kernel, dim3(NE / 4), dim3(256), 0, stream,
                       emb, en10, emax2);
    hipLaunchKernelGGL(check_fill_kernel, dim3(NTOK / 4), dim3(256), 0, stream,
                       z, emax2, out, flags);
    hipLaunchKernelGGL(prep_pack_kernel, dim3(64), dim3(512), 0, stream,
                       emb, embp);
    hipLaunchKernelGGL(sq_gemm_kernel, dim3(NTOK / BM), dim3(1024), 0, stream,
                       z, embp, en10, flags, out);
}

// Round 9
// 39.126 us; speedup vs baseline: 1.3982x; 1.3982x over previous
//
#include <hip/hip_runtime.h>

#define NTOK 32768
#define NE   1024
#define DD   256

typedef __attribute__((ext_vector_type(4))) float f32x4;

// ---- prep: en[row] = ||emb_row||^2 (plain fp32, no atomics) ----
__global__ __launch_bounds__(256) void prep_norm_kernel(
    const float* __restrict__ emb, float* __restrict__ en)
{
    const int row = blockIdx.x * 4 + (threadIdx.x >> 6);   // one wave per row
    const int q = threadIdx.x & 63;
    f32x4 v = *(const f32x4*)(emb + (size_t)row * DD + q * 4);
    float ss = v.x * v.x + v.y * v.y + v.z * v.z + v.w * v.w;
#pragma unroll
    for (int off = 32; off; off >>= 1) ss += __shfl_xor(ss, off, 64);
    if (q == 0) en[row] = ss;
}

// ---- exact fp32 GEMV + softmax fallback for one non-saturated row ----
// Wave-uniform call (ss is wave-reduced, rhs uniform). Lane l owns codes
// l*16 .. l*16+15, processed in 4 chunks of 4 to bound register use.
__device__ __attribute__((noinline)) void slow_row(
    const float* __restrict__ emb, float* __restrict__ out,
    int row, float ss, f32x4 v, int l)
{
    const int c0 = l * 16;
    float acc[16];
    float s = 0.f;
#pragma unroll
    for (int ch = 0; ch < 4; ++ch) {
        float dot[4] = {0.f, 0.f, 0.f, 0.f};
        float ene[4] = {0.f, 0.f, 0.f, 0.f};
        for (int d4 = 0; d4 < 64; ++d4) {
            f32x4 zz;
            zz.x = __shfl(v.x, d4); zz.y = __shfl(v.y, d4);
            zz.z = __shfl(v.z, d4); zz.w = __shfl(v.w, d4);
#pragma unroll
            for (int c = 0; c < 4; ++c) {
                f32x4 ev = *(const f32x4*)(emb + (size_t)(c0 + ch * 4 + c) * DD + d4 * 4);
                dot[c] = fmaf(zz.x, ev.x, fmaf(zz.y, ev.y,
                         fmaf(zz.z, ev.z, fmaf(zz.w, ev.w, dot[c]))));
                ene[c] = fmaf(ev.x, ev.x, fmaf(ev.y, ev.y,
                         fmaf(ev.z, ev.z, fmaf(ev.w, ev.w, ene[c]))));
            }
        }
#pragma unroll
        for (int c = 0; c < 4; ++c) {
            const float d = ss + ene[c] - 2.0f * dot[c];
            const float u = 10.0f * expf(-10.0f * d);   // u in (0,10]
            const float e = expf(u);
            acc[ch * 4 + c] = e;
            s += e;
        }
    }
#pragma unroll
    for (int off = 32; off; off >>= 1) s += __shfl_xor(s, off, 64);
    const float inv = 1.0f / s;
#pragma unroll
    for (int ch = 0; ch < 4; ++ch) {
        f32x4 o = { acc[ch * 4] * inv, acc[ch * 4 + 1] * inv,
                    acc[ch * 4 + 2] * inv, acc[ch * 4 + 3] * inv };
        *(f32x4*)(out + (size_t)row * NE + c0 + ch * 4) = o;
    }
}

// ---- main: per-wave saturation check + uniform fill (or exact fallback) ----
// Row n: ||z_n||^2 >= (3+E)^2 with E = max||e||  =>  d >= 9 for every code
// =>  u = 10*exp(-10d) <= 8e-39  =>  exp(u) == 1.0 exactly in fp32 AND fp64
// =>  softmax row is bit-exactly 1/1024.
// grid 2048 x 256 thr, <=64 VGPR -> whole grid resident in one occupancy round.
// No LDS, no barriers, no atomics.
__global__ __launch_bounds__(256, 8) void sq_main_kernel(
    const float* __restrict__ z, const float* __restrict__ emb,
    const float* __restrict__ en, float* __restrict__ out)
{
    const int w  = threadIdx.x >> 6;
    const int l  = threadIdx.x & 63;
    const int r0 = (blockIdx.x * 4 + w) * 4;    // 4 contiguous rows per wave

    // issue the 4 independent z-row loads first (latency overlap)
    f32x4 v[4];
#pragma unroll
    for (int k = 0; k < 4; ++k)
        v[k] = *(const f32x4*)(z + (size_t)(r0 + k) * DD + l * 4);

    // E^2 = max ||e||^2 over the 1024 codes (en: 4 KB, L2-broadcast)
    float m = 0.f;
#pragma unroll
    for (int i = 0; i < 4; ++i) {
        f32x4 q = *(const f32x4*)(en + i * 256 + l * 4);
        m = fmaxf(m, fmaxf(fmaxf(q.x, q.y), fmaxf(q.z, q.w)));
    }
#pragma unroll
    for (int off = 32; off; off >>= 1) m = fmaxf(m, __shfl_xor(m, off, 64));
    const float E   = sqrtf(m);
    const float rhs = (3.0f + E) * (3.0f + E);

    // wave-reduced row norms (4 interleaved butterflies, ILP)
    float ss[4];
#pragma unroll
    for (int k = 0; k < 4; ++k)
        ss[k] = v[k].x * v[k].x + v[k].y * v[k].y + v[k].z * v[k].z + v[k].w * v[k].w;
#pragma unroll
    for (int off = 32; off; off >>= 1)
#pragma unroll
        for (int k = 0; k < 4; ++k) ss[k] += __shfl_xor(ss[k], off, 64);

    const float c = 0.0009765625f;   // 1/1024 exactly
    const f32x4 cv = {c, c, c, c};
#pragma unroll
    for (int k = 0; k < 4; ++k) {
        if (ss[k] >= rhs) {          // wave-uniform branch
            float* ob = out + (size_t)(r0 + k) * NE + l * 4;
#pragma unroll
            for (int i = 0; i < 4; ++i)
                __builtin_nontemporal_store(cv, (f32x4*)(ob + i * 256));
        } else {
            slow_row(emb, out, r0 + k, ss[k], v[k], l);
        }
    }
}

extern "C" void kernel_launch(void* const* d_in, const int* in_sizes, int n_in,
                              void* d_out, int out_size, void* d_ws, size_t ws_size,
                              hipStream_t stream) {
    (void)in_sizes; (void)n_in; (void)out_size; (void)ws_size;
    const float* z   = (const float*)d_in[0];
    const float* emb = (const float*)d_in[1];
    float* out = (float*)d_out;
    float* en  = (float*)d_ws;   // 4 KB

    hipLaunchKernelGGL(prep_norm_kernel, dim3(NE / 4), dim3(256), 0, stream,
                       emb, en);
    hipLaunchKernelGGL(sq_main_kernel, dim3(NTOK / 16), dim3(256), 0, stream,
                       z, emb, en, out);
}

// Round 10
// 35.321 us; speedup vs baseline: 1.5488x; 1.1077x over previous
//
#include <hip/hip_runtime.h>

#define NTOK 32768
#define NE   1024
#define DD   256

typedef __attribute__((ext_vector_type(4))) float f32x4;

// ---- prep: pmax[b] = max over 16 emb rows of ||e_row||^2  (64 blocks) ----
__global__ __launch_bounds__(256) void prep_norm_kernel(
    const float* __restrict__ emb, float* __restrict__ pmax)
{
    __shared__ float sm[4];
    const int w = threadIdx.x >> 6;
    const int l = threadIdx.x & 63;
    float m = 0.f;
#pragma unroll
    for (int k = 0; k < 4; ++k) {
        const int row = blockIdx.x * 16 + w * 4 + k;
        f32x4 v = *(const f32x4*)(emb + (size_t)row * DD + l * 4);
        float ss = v.x * v.x + v.y * v.y + v.z * v.z + v.w * v.w;
#pragma unroll
        for (int off = 32; off; off >>= 1) ss += __shfl_xor(ss, off, 64);
        m = fmaxf(m, ss);
    }
    if (l == 0) sm[w] = m;
    __syncthreads();
    if (threadIdx.x == 0)
        pmax[blockIdx.x] = fmaxf(fmaxf(sm[0], sm[1]), fmaxf(sm[2], sm[3]));
}

// ---- exact fp32 GEMV + softmax fallback for one non-saturated row ----
// Wave-uniform call. Lane l owns codes l*16..l*16+15, in 4 chunks of 4.
__device__ __attribute__((noinline)) void slow_row(
    const float* __restrict__ emb, float* __restrict__ out,
    int row, float ss, f32x4 v, int l)
{
    const int c0 = l * 16;
    float acc[16];
    float s = 0.f;
#pragma unroll
    for (int ch = 0; ch < 4; ++ch) {
        float dot[4] = {0.f, 0.f, 0.f, 0.f};
        float ene[4] = {0.f, 0.f, 0.f, 0.f};
        for (int d4 = 0; d4 < 64; ++d4) {
            f32x4 zz;
            zz.x = __shfl(v.x, d4); zz.y = __shfl(v.y, d4);
            zz.z = __shfl(v.z, d4); zz.w = __shfl(v.w, d4);
#pragma unroll
            for (int c = 0; c < 4; ++c) {
                f32x4 ev = *(const f32x4*)(emb + (size_t)(c0 + ch * 4 + c) * DD + d4 * 4);
                dot[c] = fmaf(zz.x, ev.x, fmaf(zz.y, ev.y,
                         fmaf(zz.z, ev.z, fmaf(zz.w, ev.w, dot[c]))));
                ene[c] = fmaf(ev.x, ev.x, fmaf(ev.y, ev.y,
                         fmaf(ev.z, ev.z, fmaf(ev.w, ev.w, ene[c]))));
            }
        }
#pragma unroll
        for (int c = 0; c < 4; ++c) {
            const float d = ss + ene[c] - 2.0f * dot[c];
            const float u = 10.0f * expf(-10.0f * d);   // u in (0,10]
            const float e = expf(u);
            acc[ch * 4 + c] = e;
            s += e;
        }
    }
#pragma unroll
    for (int off = 32; off; off >>= 1) s += __shfl_xor(s, off, 64);
    const float inv = 1.0f / s;
#pragma unroll
    for (int ch = 0; ch < 4; ++ch) {
        f32x4 o = { acc[ch * 4] * inv, acc[ch * 4 + 1] * inv,
                    acc[ch * 4 + 2] * inv, acc[ch * 4 + 3] * inv };
        *(f32x4*)(out + (size_t)row * NE + c0 + ch * 4) = o;
    }
}

// ---- main: per-row saturation check + uniform fill (or exact fallback) ----
// Row n: ||z_n||^2 >= (3+E)^2, E = max||e||  =>  d >= 9 for every code
// => u = 10*exp(-10d) <= 8e-39 << 2^-53  =>  exp(u) == 1.0 exactly in
// fp32 AND fp64  =>  softmax row is bit-exactly 1/1024.
// 2 rows/wave, 4096 blocks (16384 waves = 2 residency rounds for pipelining).
// No LDS, no barriers, no atomics; plain stores (match fill-kernel path).
__global__ __launch_bounds__(256, 8) void sq_main_kernel(
    const float* __restrict__ z, const float* __restrict__ emb,
    const float* __restrict__ pmax, float* __restrict__ out)
{
    const int w  = threadIdx.x >> 6;
    const int l  = threadIdx.x & 63;
    const int r0 = (blockIdx.x * 4 + w) * 2;    // 2 contiguous rows per wave

    // issue the 2 independent z-row loads first (latency overlap)
    f32x4 v0 = *(const f32x4*)(z + (size_t)r0 * DD + l * 4);
    f32x4 v1 = *(const f32x4*)(z + (size_t)(r0 + 1) * DD + l * 4);

    // E^2 = max ||e||^2: one dword per lane from pmax[64] + butterfly
    float m = pmax[l];
#pragma unroll
    for (int off = 32; off; off >>= 1) m = fmaxf(m, __shfl_xor(m, off, 64));
    const float E   = sqrtf(m);
    const float rhs = (3.0f + E) * (3.0f + E);

    // wave-reduced row norms (2 interleaved butterflies)
    float s0 = v0.x * v0.x + v0.y * v0.y + v0.z * v0.z + v0.w * v0.w;
    float s1 = v1.x * v1.x + v1.y * v1.y + v1.z * v1.z + v1.w * v1.w;
#pragma unroll
    for (int off = 32; off; off >>= 1) {
        s0 += __shfl_xor(s0, off, 64);
        s1 += __shfl_xor(s1, off, 64);
    }

    const float c = 0.0009765625f;   // 1/1024 exactly
    const f32x4 cv = {c, c, c, c};
    if (s0 >= rhs) {                 // wave-uniform branch
        float* ob = out + (size_t)r0 * NE + l * 4;
#pragma unroll
        for (int i = 0; i < 4; ++i) *(f32x4*)(ob + i * 256) = cv;
    } else {
        slow_row(emb, out, r0, s0, v0, l);
    }
    if (s1 >= rhs) {
        float* ob = out + (size_t)(r0 + 1) * NE + l * 4;
#pragma unroll
        for (int i = 0; i < 4; ++i) *(f32x4*)(ob + i * 256) = cv;
    } else {
        slow_row(emb, out, r0 + 1, s1, v1, l);
    }
}

extern "C" void kernel_launch(void* const* d_in, const int* in_sizes, int n_in,
                              void* d_out, int out_size, void* d_ws, size_t ws_size,
                              hipStream_t stream) {
    (void)in_sizes; (void)n_in; (void)out_size; (void)ws_size;
    const float* z   = (const float*)d_in[0];
    const float* emb = (const float*)d_in[1];
    float* out = (float*)d_out;
    float* pmax = (float*)d_ws;   // 64 floats

    hipLaunchKernelGGL(prep_norm_kernel, dim3(64), dim3(256), 0, stream,
                       emb, pmax);
    hipLaunchKernelGGL(sq_main_kernel, dim3(NTOK / 8), dim3(256), 0, stream,
                       z, emb, pmax, out);
}